// Round 6
// baseline (1037.803 us; speedup 1.0000x reference)
//
#include <hip/hip_runtime.h>

// ---------------------------------------------------------------------------
// Atten2Map on MI355X (gfx950) — R5: fused single-kernel pipeline
// shapes: nb=4 nloc=256 nnei=128 ni=128, ND=32 NH=8, NCH=512, NBL=1024
//
// Kd : detect nlist_mask dtype (int32 vs byte-packed)      -> flag in ws
// K0 : Wt[c][t] = W[t][c] * 32^-0.25, split bf16 hi/lo     -> ws (512 KB)
// K0b: g2 split bf16 hi/lo (elementwise)                   -> ws (134 MB)
// KF : per-(b,l) fused: split-bf16 MFMA GEMM -> bf16 LDS slab [h][row][d]
//      (XOR-swizzled) -> per-head Q/K frags in regs -> QK^T (1 MFMA/tile)
//      -> masked softmax *sw*sw -> S8 LDS (reuses slab memory) ->
//      *h2h2t -> h-contiguous 32B stores to out[b,l,q,k,h].
//
// R1: mask arrives int32 (verified R4; runtime detector kept for safety).
// R4: passed, 842 us, absmax 2.4e-4. R5 kills the 536 MB QK ws round-trip.
// R6: resubmit of R5 (round lost to GPU acquisition timeout; unverified).
// ---------------------------------------------------------------------------

typedef __attribute__((ext_vector_type(8))) short bf16x8;
typedef __attribute__((ext_vector_type(4))) float f32x4;

#define NBL        1024
#define FLAG_BYTES 256
#define WT_SHORTS  (512 * 128)           // 65536 per half
#define G2_ELEMS   (1024 * 128 * 128)    // 16,777,216

__device__ __forceinline__ unsigned short f2bf(float x) {
    unsigned u = __builtin_bit_cast(unsigned, x);
    u += 0x7FFFu + ((u >> 16) & 1u);              // RNE
    return (unsigned short)(u >> 16);
}
__device__ __forceinline__ float bf2f(unsigned short b) {
    unsigned u = ((unsigned)b) << 16;
    return __builtin_bit_cast(float, u);
}

// ------------------------------- Kd ----------------------------------------
__global__ void k_detect_mask(const unsigned int* __restrict__ m, int nwords,
                              int* __restrict__ flag) {
    __shared__ int f;
    if (threadIdx.x == 0) f = 0;
    __syncthreads();
    int acc = 0;
    for (int i = threadIdx.x; i < nwords; i += blockDim.x)
        acc |= (m[i] & ~1u) ? 1 : 0;
    if (acc) atomicOr(&f, 1);
    __syncthreads();
    if (threadIdx.x == 0) *flag = f;
}

// ------------------------------- K0 ----------------------------------------
__global__ void k0_prep_w(const float* __restrict__ W,
                          unsigned short* __restrict__ wt_hi,
                          unsigned short* __restrict__ wt_lo) {
    int g = blockIdx.x * 256 + threadIdx.x;        // 65536 elements
    int c = g >> 7, t = g & 127;
    float w = W[t * 512 + c] * 0.42044820762685725f;   // 32^-0.25
    unsigned short hb = f2bf(w);
    wt_hi[g] = hb;
    wt_lo[g] = f2bf(w - bf2f(hb));
}

// ------------------------------- K0b ---------------------------------------
__global__ void k0b_split_g2(const float* __restrict__ g2,
                             unsigned short* __restrict__ gh,
                             unsigned short* __restrict__ gl) {
    size_t i = ((size_t)blockIdx.x * 256 + threadIdx.x) * 4;
    float4 v = *(const float4*)(g2 + i);
    unsigned short h0 = f2bf(v.x), h1 = f2bf(v.y), h2_ = f2bf(v.z), h3 = f2bf(v.w);
    ushort4 hv = {h0, h1, h2_, h3};
    ushort4 lv = {f2bf(v.x - bf2f(h0)), f2bf(v.y - bf2f(h1)),
                  f2bf(v.z - bf2f(h2_)), f2bf(v.w - bf2f(h3))};
    *(ushort4*)(gh + i) = hv;
    *(ushort4*)(gl + i) = lv;
}

// ------------------------------- KF ----------------------------------------
// grid = 1024 (one WG per (b,l)); 512 threads = 8 waves.
// LDS: U = union{ slab: Qs[8][128][32] + Ks[8][128][32] bf16 (128 KB, XOR-swz)
//                 S8[32][1152] f32 (147 KB) } + tables (~4.5 KB).
__launch_bounds__(512, 2)
__global__ void k_fused(const unsigned short* __restrict__ g2h,
                        const unsigned short* __restrict__ g2l,
                        const unsigned short* __restrict__ wh,
                        const unsigned short* __restrict__ wl,
                        const float* __restrict__ h2,
                        const int* __restrict__ msk,
                        const float* __restrict__ sw,
                        const int* __restrict__ mask_is_bytes,
                        float* __restrict__ outp) {
    __shared__ __align__(16) char U[147456];      // slab (128K) / S8 (144K)
    __shared__ float h2t[3][128];
    __shared__ float rowsw[128], colbias[128], colsw[128];

    const int tid  = threadIdx.x;
    const int lane = tid & 63;
    const int wv   = tid >> 6;
    const int colk = lane & 15;
    const int dgrp = lane >> 4;
    const int wm   = wv >> 2;          // GEMM: 0..1 -> 64 j-rows
    const int wn   = wv & 3;           // GEMM: 0..3 -> 128 c-cols
    const int h    = wv;               // attn phase: wave = head
    const int bl   = blockIdx.x;

    // ---- tables ----
    if (tid < 128) {
        int  idx = bl * 128 + tid;
        bool mk  = (*mask_is_bytes)
                     ? (((const unsigned char*)msk)[idx] != 0)
                     : (msk[idx] != 0);
        float s  = sw[idx];
        rowsw[tid]   = mk ? s : 0.0f;
        colbias[tid] = mk ? 0.0f : -1e30f;
        colsw[tid]   = s;
    }
    if (tid < 384) {
        int c = tid >> 7, j = tid & 127;
        h2t[c][j] = h2[(size_t)bl * 384 + j * 3 + c];
    }

    // ---- phase 1: GEMM g2 @ Wt -> bf16 slab in LDS ----
    // slab element (c, j): hh=c&15 (<8 -> Qs[hh], else Ks[hh-8]), d=c>>4.
    // byte = sel(hh) + hh7*8192 + ((j*64 + d*2) ^ (hh7<<4))
    const unsigned short* Ah = g2h + (size_t)bl * 16384;
    const unsigned short* Al = g2l + (size_t)bl * 16384;
    char* myslab = U + ((colk & 8) ? 65536 : 0) + (colk & 7) * 8192;
    const int hx = (colk & 7) << 4;

#pragma unroll
    for (int nb = 0; nb < 4; ++nb) {
        f32x4 acc[4][2];
#pragma unroll
        for (int m = 0; m < 4; ++m)
#pragma unroll
            for (int n = 0; n < 2; ++n) acc[m][n] = (f32x4)0.0f;

#pragma unroll
        for (int kk = 0; kk < 4; ++kk) {
            const int t0 = kk * 32 + dgrp * 8;
            bf16x8 ah[4], al[4], bh[2], bl_[2];
#pragma unroll
            for (int m = 0; m < 4; ++m) {
                int j = wm * 64 + m * 16 + colk;
                ah[m] = *(const bf16x8*)(Ah + j * 128 + t0);
                al[m] = *(const bf16x8*)(Al + j * 128 + t0);
            }
#pragma unroll
            for (int n = 0; n < 2; ++n) {
                int c = nb * 128 + wn * 32 + n * 16 + colk;
                bh[n]  = *(const bf16x8*)(wh + c * 128 + t0);
                bl_[n] = *(const bf16x8*)(wl + c * 128 + t0);
            }
#pragma unroll
            for (int m = 0; m < 4; ++m)
#pragma unroll
                for (int n = 0; n < 2; ++n) {
                    acc[m][n] = __builtin_amdgcn_mfma_f32_16x16x32_bf16(ah[m], bh[n],  acc[m][n], 0, 0, 0);
                    acc[m][n] = __builtin_amdgcn_mfma_f32_16x16x32_bf16(ah[m], bl_[n], acc[m][n], 0, 0, 0);
                    acc[m][n] = __builtin_amdgcn_mfma_f32_16x16x32_bf16(al[m], bh[n],  acc[m][n], 0, 0, 0);
                }
        }
        // write packed bf16 pair (d0, d0+1) per (m, r)
        const int d0 = nb * 8 + wn * 2;   // even
#pragma unroll
        for (int m = 0; m < 4; ++m)
#pragma unroll
            for (int r = 0; r < 4; ++r) {
                int j = wm * 64 + m * 16 + dgrp * 4 + r;
                unsigned v = (unsigned)f2bf(acc[m][0][r]) |
                             ((unsigned)f2bf(acc[m][1][r]) << 16);
                *(unsigned*)(myslab + ((j * 64 + d0 * 2) ^ hx)) = v;
            }
    }

    __syncthreads();

    // ---- phase 2: preload per-head Q/K fragments + tables to regs ----
    float cbias[8], cswr[8];
#pragma unroll
    for (int n = 0; n < 8; ++n) {
        int k = n * 16 + colk;
        cbias[n] = colbias[k];
        cswr[n]  = colsw[k];
    }

    const int hy = h << 4;
    bf16x8 qf[4][2], kf[8];
#pragma unroll
    for (int qt = 0; qt < 4; ++qt)
#pragma unroll
        for (int m = 0; m < 2; ++m) {
            int qrow = qt * 32 + m * 16 + colk;
            qf[qt][m] = *(const bf16x8*)(U + h * 8192 +
                          ((qrow * 64 + dgrp * 16) ^ hy));
        }
#pragma unroll
    for (int n = 0; n < 8; ++n) {
        int krow = n * 16 + colk;
        kf[n] = *(const bf16x8*)(U + 65536 + h * 8192 +
                  ((krow * 64 + dgrp * 16) ^ hy));
    }

    __syncthreads();   // slab dead -> U becomes S8[32][1152]

    float* S8 = (float*)U;

    // ---- phase 3: per-head QK^T + softmax + epilogue ----
    for (int qt = 0; qt < 4; ++qt) {
        f32x4 acc[2][8];
#pragma unroll
        for (int m = 0; m < 2; ++m)
#pragma unroll
            for (int n = 0; n < 8; ++n) acc[m][n] = (f32x4)0.0f;

#pragma unroll
        for (int m = 0; m < 2; ++m)
#pragma unroll
            for (int n = 0; n < 8; ++n)
                acc[m][n] = __builtin_amdgcn_mfma_f32_16x16x32_bf16(
                                qf[qt][m], kf[n], acc[m][n], 0, 0, 0);

        // masked softmax over k per q-row, scale, stage to S8
#pragma unroll
        for (int m = 0; m < 2; ++m) {
#pragma unroll
            for (int r = 0; r < 4; ++r) {
                float mx = -1e30f;
#pragma unroll
                for (int n = 0; n < 8; ++n) mx = fmaxf(mx, acc[m][n][r] + cbias[n]);
#pragma unroll
                for (int off = 1; off < 16; off <<= 1) mx = fmaxf(mx, __shfl_xor(mx, off));
                float p[8], sum = 0.0f;
#pragma unroll
                for (int n = 0; n < 8; ++n) {
                    p[n] = __expf(acc[m][n][r] + cbias[n] - mx);
                    sum += p[n];
                }
#pragma unroll
                for (int off = 1; off < 16; off <<= 1) sum += __shfl_xor(sum, off);
                int   qlocal = m * 16 + dgrp * 4 + r;
                float scale  = rowsw[qt * 32 + qlocal] / sum;
#pragma unroll
                for (int n = 0; n < 8; ++n)
                    S8[qlocal * 1152 + (n * 16 + colk) * 9 + h] = p[n] * scale * cswr[n];
            }
        }
        __syncthreads();

        // epilogue: h-contiguous 32B stores, * h2h2t[q][k]
        {
            int kx = (h & 1) * 64 + lane;
#pragma unroll
            for (int it = 0; it < 8; ++it) {
                int qlocal = (h >> 1) * 8 + it;
                int q = qt * 32 + qlocal;
                const float* srow = S8 + qlocal * 1152 + kx * 9;
                float hh = (h2t[0][q] * h2t[0][kx] + h2t[1][q] * h2t[1][kx] +
                            h2t[2][q] * h2t[2][kx]) * 0.57735026918962576f;
                float4 o0 = {srow[0] * hh, srow[1] * hh, srow[2] * hh, srow[3] * hh};
                float4 o1 = {srow[4] * hh, srow[5] * hh, srow[6] * hh, srow[7] * hh};
                size_t ob = (((size_t)bl * 128 + q) * 128 + kx) * 8;
                *(float4*)(outp + ob)     = o0;
                *(float4*)(outp + ob + 4) = o1;
            }
        }
        __syncthreads();
    }
}

// ------------------------------- host --------------------------------------
extern "C" void kernel_launch(void* const* d_in, const int* in_sizes, int n_in,
                              void* d_out, int out_size, void* d_ws, size_t ws_size,
                              hipStream_t stream) {
    const float* g2  = (const float*)d_in[0];
    const float* h2  = (const float*)d_in[1];
    const int*   mk  = (const int*)d_in[2];
    const float* sw  = (const float*)d_in[3];
    const float* W   = (const float*)d_in[4];
    float*       out = (float*)d_out;
    char*        ws  = (char*)d_ws;

    int*            flag  = (int*)ws;
    unsigned short* wt_hi = (unsigned short*)(ws + FLAG_BYTES);
    unsigned short* wt_lo = wt_hi + WT_SHORTS;
    unsigned short* g2hi  = wt_lo + WT_SHORTS;
    unsigned short* g2lo  = g2hi + G2_ELEMS;

    k_detect_mask<<<dim3(1), dim3(256), 0, stream>>>(
        (const unsigned int*)mk, in_sizes[2] / 4, flag);
    k0_prep_w<<<dim3(256), dim3(256), 0, stream>>>(W, wt_hi, wt_lo);
    k0b_split_g2<<<dim3(G2_ELEMS / 1024), dim3(256), 0, stream>>>(g2, g2hi, g2lo);
    k_fused<<<dim3(NBL), dim3(512), 0, stream>>>(
        g2hi, g2lo, wt_hi, wt_lo, h2, mk, sw, flag, out);
}